// Round 9
// baseline (576.000 us; speedup 1.0000x reference)
//
#include <hip/hip_runtime.h>

constexpr int B = 8, S = 2048, D = 256;
constexpr int TQ = 32;              // query rows per block
constexpr float SCALE = 0.0625f;    // 1/sqrt(256)
constexpr int PST = 264;            // P-tile col stride (256 + 8 pad)

typedef __attribute__((ext_vector_type(8))) short bf16x8;  // 8 bf16 in 4 VGPRs
typedef __attribute__((ext_vector_type(4))) float f32x4;

__device__ __forceinline__ short f2bf(float f) {
    union { float f; unsigned u; } c; c.f = f;
    unsigned u = c.u + 0x7fffu + ((c.u >> 16) & 1u);   // RNE
    return (short)(u >> 16);
}

// ---- minimal pre-pass: convK | transposeV only ----
__global__ __launch_bounds__(256) void prepass(
    const float* __restrict__ k, const float* __restrict__ v,
    short* __restrict__ kb, short* __restrict__ vtb)
{
    __shared__ float tile[64][65];
    const int blk = blockIdx.x;
    const int tid = threadIdx.x;

    if (blk < 4096) {
        int i = blk * 256 + tid;
        float4 x = ((const float4*)k)[i];
        short4 o; o.x = f2bf(x.x); o.y = f2bf(x.y); o.z = f2bf(x.z); o.w = f2bf(x.w);
        ((short4*)kb)[i] = o;
    } else {
        int blk2 = blk - 4096;
        int b = blk2 >> 7, rem = blk2 & 127;
        int d0 = (rem & 3) * 64, k0 = (rem >> 2) * 64;
        int tr = tid >> 4, tc = tid & 15;
        const float* vb = v + (size_t)b * S * D;
        #pragma unroll
        for (int r = 0; r < 4; ++r) {
            int key = r * 16 + tr;
            float4 x = *(const float4*)(vb + (size_t)(k0 + key) * D + d0 + tc * 4);
            tile[key][tc * 4 + 0] = x.x; tile[key][tc * 4 + 1] = x.y;
            tile[key][tc * 4 + 2] = x.z; tile[key][tc * 4 + 3] = x.w;
        }
        __syncthreads();
        short* vtbb = vtb + (size_t)b * D * S;
        #pragma unroll
        for (int r = 0; r < 4; ++r) {
            int d = r * 16 + tr;
            short4 o;
            o.x = f2bf(tile[tc * 4 + 0][d]); o.y = f2bf(tile[tc * 4 + 1][d]);
            o.z = f2bf(tile[tc * 4 + 2][d]); o.w = f2bf(tile[tc * 4 + 3][d]);
            *(short4*)(vtbb + (size_t)(d0 + d) * S + k0 + tc * 4) = o;
        }
    }
}

// ---- main fused kernel: two-sweep flash restructure ----
// Sweep 1 (per 256-key tile): QK^T fragment (acc 16 floats, not 128), mask
//   (int4 loads, bits packed to 2xu64), exp, rsum accumulate. No LDS, no P.
// Sweep 2: recompute scores per tile (QK^T twice; MFMA-busy was only 13 us),
//   normalize, write attn float4, stage 16 KB P-tile in dbuf LDS, PV per tile.
// Kills the 32x2048 slab: LDS 128.5->34.8 KB, acc regs 128->16 -> (512,4)
//   gives 2 blocks/CU; streams interleave with MFMA at tile granularity.
// Swapped QK^T (R7): acc[mt][nt][r] = S^T[key][q]. XCD-batch affinity (R5).
__global__ __launch_bounds__(512, 4) void attn_mfma(
    const float* __restrict__ qf, const short* __restrict__ kb,
    const short* __restrict__ vtb, const int* __restrict__ maskg,
    float* __restrict__ outg, float* __restrict__ attng)
{
    const int b = blockIdx.x & 7;              // XCD-affine batch
    const int i0 = (blockIdx.x >> 3) * TQ;     // q-tile within batch
    const int tid = threadIdx.x;
    const int wave = tid >> 6, lane = tid & 63;
    const int quad = lane >> 4, l16 = lane & 15;

    __shared__ short p_lds[2][TQ][PST];        // 33.8 KB double-buffered P tile
    __shared__ float red[8][TQ];

    // ---------- Q fp32 -> bf16 in-register (reused by both sweeps) ----------
    bf16x8 aq[2][8];
    const float* qbase = qf + ((size_t)b * S + i0) * D;
    #pragma unroll
    for (int mt = 0; mt < 2; ++mt)
        #pragma unroll
        for (int ks = 0; ks < 8; ++ks) {
            const float* p = qbase + (size_t)(mt * 16 + l16) * D + ks * 32 + quad * 8;
            float4 x0 = *(const float4*)p;
            float4 x1 = *(const float4*)(p + 4);
            bf16x8 a;
            a[0] = f2bf(x0.x); a[1] = f2bf(x0.y); a[2] = f2bf(x0.z); a[3] = f2bf(x0.w);
            a[4] = f2bf(x1.x); a[5] = f2bf(x1.y); a[6] = f2bf(x1.z); a[7] = f2bf(x1.w);
            aq[mt][ks] = a;
        }

    const short* kbase = kb + (size_t)b * S * D;
    const int* mrow0 = maskg + ((size_t)b * S + i0 + l16) * S + quad * 4;
    const int* mrow1 = mrow0 + (size_t)16 * S;

    // ---------- sweep 1: rsum + mask-bit pack (no LDS, no P kept) ----------
    float rsum[2] = {0.f, 0.f};
    unsigned long long mb[2] = {0ull, 0ull};
    #pragma unroll 1
    for (int t = 0; t < 8; ++t) {
        const int kq0 = t * 256 + wave * 32;   // this wave's 32 keys in tile t
        int4 m00 = *(const int4*)(mrow0 + kq0);
        int4 m01 = *(const int4*)(mrow0 + kq0 + 16);
        int4 m10 = *(const int4*)(mrow1 + kq0);
        int4 m11 = *(const int4*)(mrow1 + kq0 + 16);
        f32x4 acc2[2][2];
        #pragma unroll
        for (int mt = 0; mt < 2; ++mt)
            #pragma unroll
            for (int nt = 0; nt < 2; ++nt)
                acc2[mt][nt] = f32x4{0.f, 0.f, 0.f, 0.f};
        #pragma unroll
        for (int nt = 0; nt < 2; ++nt) {
            bf16x8 bk[8];
            #pragma unroll
            for (int ks = 0; ks < 8; ++ks)
                bk[ks] = *(const bf16x8*)(kbase + (size_t)(kq0 + nt * 16 + l16) * D + ks * 32 + quad * 8);
            #pragma unroll
            for (int ks = 0; ks < 8; ++ks) {
                acc2[0][nt] = __builtin_amdgcn_mfma_f32_16x16x32_bf16(bk[ks], aq[0][ks], acc2[0][nt], 0, 0, 0);
                acc2[1][nt] = __builtin_amdgcn_mfma_f32_16x16x32_bf16(bk[ks], aq[1][ks], acc2[1][nt], 0, 0, 0);
            }
        }
        const int me[2][2][4] = {
            {{m00.x, m00.y, m00.z, m00.w}, {m01.x, m01.y, m01.z, m01.w}},
            {{m10.x, m10.y, m10.z, m10.w}, {m11.x, m11.y, m11.z, m11.w}}};
        #pragma unroll
        for (int mt = 0; mt < 2; ++mt)
            #pragma unroll
            for (int nt = 0; nt < 2; ++nt)
                #pragma unroll
                for (int r = 0; r < 4; ++r) {
                    const bool on = me[mt][nt][r] != 0;
                    mb[mt] |= (unsigned long long)(on ? 1 : 0) << (t * 8 + nt * 4 + r);
                    float e = on ? __expf(acc2[mt][nt][r] * SCALE) : 0.0f;  // exp(-1e9)->0 == ref
                    rsum[mt] += e;
                }
    }

    // ---------- reduce row-sums: 4 quads (shfl) then 8 waves (LDS) ----------
    #pragma unroll
    for (int mt = 0; mt < 2; ++mt) {
        float v = rsum[mt];
        v += __shfl_xor(v, 16); v += __shfl_xor(v, 32);
        if (quad == 0) red[wave][mt * 16 + l16] = v;
    }
    __syncthreads();

    float inv[2];
    #pragma unroll
    for (int mt = 0; mt < 2; ++mt) {
        float tot = 0.f;
        #pragma unroll
        for (int w = 0; w < 8; ++w) tot += red[w][mt * 16 + l16];
        inv[mt] = 1.0f / tot;
    }

    // ---------- sweep 2: recompute scores, attn write, P-tile, PV ----------
    f32x4 oacc[2][2];
    #pragma unroll
    for (int mt = 0; mt < 2; ++mt)
        #pragma unroll
        for (int nc = 0; nc < 2; ++nc) oacc[mt][nc] = f32x4{0.f, 0.f, 0.f, 0.f};

    const short* vbase = vtb + (size_t)b * D * S;
    const int nb = wave * 32;

    #pragma unroll 1
    for (int t = 0; t < 8; ++t) {
        const int kq0 = t * 256 + wave * 32;
        f32x4 acc2[2][2];
        #pragma unroll
        for (int mt = 0; mt < 2; ++mt)
            #pragma unroll
            for (int nt = 0; nt < 2; ++nt)
                acc2[mt][nt] = f32x4{0.f, 0.f, 0.f, 0.f};
        #pragma unroll
        for (int nt = 0; nt < 2; ++nt) {
            bf16x8 bk[8];
            #pragma unroll
            for (int ks = 0; ks < 8; ++ks)
                bk[ks] = *(const bf16x8*)(kbase + (size_t)(kq0 + nt * 16 + l16) * D + ks * 32 + quad * 8);
            #pragma unroll
            for (int ks = 0; ks < 8; ++ks) {
                acc2[0][nt] = __builtin_amdgcn_mfma_f32_16x16x32_bf16(bk[ks], aq[0][ks], acc2[0][nt], 0, 0, 0);
                acc2[1][nt] = __builtin_amdgcn_mfma_f32_16x16x32_bf16(bk[ks], aq[1][ks], acc2[1][nt], 0, 0, 0);
            }
        }
        // normalize, write attn (float4, batched per row), stash P bf16 tile
        #pragma unroll
        for (int mt = 0; mt < 2; ++mt) {
            float* arow = attng + ((size_t)b * S + i0 + mt * 16 + l16) * S + kq0 + quad * 4;
            #pragma unroll
            for (int nt = 0; nt < 2; ++nt) {
                float pv[4];
                #pragma unroll
                for (int r = 0; r < 4; ++r) {
                    const bool on = (mb[mt] >> (t * 8 + nt * 4 + r)) & 1ull;
                    pv[r] = on ? __expf(acc2[mt][nt][r] * SCALE) * inv[mt] : 0.0f;
                }
                float4 p4; p4.x = pv[0]; p4.y = pv[1]; p4.z = pv[2]; p4.w = pv[3];
                short4 pb; pb.x = f2bf(pv[0]); pb.y = f2bf(pv[1]);
                pb.z = f2bf(pv[2]); pb.w = f2bf(pv[3]);
                *(float4*)(arow + nt * 16) = p4;
                *(short4*)&p_lds[t & 1][mt * 16 + l16][wave * 32 + nt * 16 + quad * 4] = pb;
            }
        }
        // raw barrier: wait LDS writes only; attn stores retire under PV below.
        asm volatile("s_waitcnt lgkmcnt(0)" ::: "memory");
        __builtin_amdgcn_s_barrier();

        // PV over this tile (wave w owns out dims [w*32, w*32+32))
        #pragma unroll
        for (int ks = 0; ks < 8; ++ks) {
            bf16x8 ap0 = *(const bf16x8*)&p_lds[t & 1][l16][ks * 32 + quad * 8];
            bf16x8 ap1 = *(const bf16x8*)&p_lds[t & 1][16 + l16][ks * 32 + quad * 8];
            bf16x8 bv0 = *(const bf16x8*)(vbase + (size_t)(nb + l16) * S + t * 256 + ks * 32 + quad * 8);
            bf16x8 bv1 = *(const bf16x8*)(vbase + (size_t)(nb + 16 + l16) * S + t * 256 + ks * 32 + quad * 8);
            oacc[0][0] = __builtin_amdgcn_mfma_f32_16x16x32_bf16(ap0, bv0, oacc[0][0], 0, 0, 0);
            oacc[0][1] = __builtin_amdgcn_mfma_f32_16x16x32_bf16(ap0, bv1, oacc[0][1], 0, 0, 0);
            oacc[1][0] = __builtin_amdgcn_mfma_f32_16x16x32_bf16(ap1, bv0, oacc[1][0], 0, 0, 0);
            oacc[1][1] = __builtin_amdgcn_mfma_f32_16x16x32_bf16(ap1, bv1, oacc[1][1], 0, 0, 0);
        }
        // no second barrier needed: next tile writes the OTHER buffer, and the
        // following tile's single barrier orders reuse of this one.
    }

    #pragma unroll
    for (int mt = 0; mt < 2; ++mt)
        #pragma unroll
        for (int nc = 0; nc < 2; ++nc)
            #pragma unroll
            for (int r = 0; r < 4; ++r) {
                int row = i0 + mt * 16 + quad * 4 + r;
                int col = nb + nc * 16 + l16;
                outg[((size_t)b * S + row) * D + col] = oacc[mt][nc][r];
            }
}

extern "C" void kernel_launch(void* const* d_in, const int* in_sizes, int n_in,
                              void* d_out, int out_size, void* d_ws, size_t ws_size,
                              hipStream_t stream) {
    const float* q    = (const float*)d_in[0];
    const float* k    = (const float*)d_in[1];
    const float* v    = (const float*)d_in[2];
    const int*   mask = (const int*)d_in[3];
    float* out  = (float*)d_out;
    float* attn = out + (size_t)B * S * D;     // tuple order: (out, attn)

    const size_t N = (size_t)B * S * D;        // 4,194,304 elements
    short* kb  = (short*)d_ws;                 // 8 MB
    short* vtb = kb + N;                       // 8 MB (transposed V)

    prepass<<<dim3(5120), 256, 0, stream>>>(k, v, kb, vtb);
    attn_mfma<<<dim3((S / TQ) * B), 512, 0, stream>>>(q, kb, vtb, mask, out, attn);
}

// Round 10
// 518.122 us; speedup vs baseline: 1.1117x; 1.1117x over previous
//
#include <hip/hip_runtime.h>

constexpr int B = 8, S = 2048, D = 256;
constexpr int TQ = 16;              // 16 q-rows/block: acc 64 AGPR + 64 VGPR = 128/wave
constexpr float SCALE = 0.0625f;    // 1/sqrt(256)
constexpr int PSTRIDE = 2056;       // 2048 + 8 bf16 pad

typedef __attribute__((ext_vector_type(8))) short bf16x8;  // 8 bf16 in 4 VGPRs
typedef __attribute__((ext_vector_type(4))) float f32x4;

__device__ __forceinline__ short f2bf(float f) {
    union { float f; unsigned u; } c; c.f = f;
    unsigned u = c.u + 0x7fffu + ((c.u >> 16) & 1u);   // RNE
    return (short)(u >> 16);
}

// ---- minimal pre-pass: convK | transposeV ----
__global__ __launch_bounds__(256) void prepass(
    const float* __restrict__ k, const float* __restrict__ v,
    short* __restrict__ kb, short* __restrict__ vtb)
{
    __shared__ float tile[64][65];
    const int blk = blockIdx.x;
    const int tid = threadIdx.x;

    if (blk < 4096) {
        int i = blk * 256 + tid;
        float4 x = ((const float4*)k)[i];
        short4 o; o.x = f2bf(x.x); o.y = f2bf(x.y); o.z = f2bf(x.z); o.w = f2bf(x.w);
        ((short4*)kb)[i] = o;
    } else {
        int blk2 = blk - 4096;
        int b = blk2 >> 7, rem = blk2 & 127;
        int d0 = (rem & 3) * 64, k0 = (rem >> 2) * 64;
        int tr = tid >> 4, tc = tid & 15;
        const float* vb = v + (size_t)b * S * D;
        #pragma unroll
        for (int r = 0; r < 4; ++r) {
            int key = r * 16 + tr;
            float4 x = *(const float4*)(vb + (size_t)(k0 + key) * D + d0 + tc * 4);
            tile[key][tc * 4 + 0] = x.x; tile[key][tc * 4 + 1] = x.y;
            tile[key][tc * 4 + 2] = x.z; tile[key][tc * 4 + 3] = x.w;
        }
        __syncthreads();
        short* vtbb = vtb + (size_t)b * D * S;
        #pragma unroll
        for (int r = 0; r < 4; ++r) {
            int d = r * 16 + tr;
            short4 o;
            o.x = f2bf(tile[tc * 4 + 0][d]); o.y = f2bf(tile[tc * 4 + 1][d]);
            o.z = f2bf(tile[tc * 4 + 2][d]); o.w = f2bf(tile[tc * 4 + 3][d]);
            *(short4*)(vtbb + (size_t)(d0 + d) * S + k0 + tc * 4) = o;
        }
    }
}

// ---- main fused kernel: 512 threads (8 waves), 1 block = 16 q-rows x 1 batch ----
// TQ=16 + (512,4): 64 AGPR acc + ~64 VGPR = fits 128/wave -> 16 waves/CU,
// 2 blocks/CU by LDS (64.8 KB). R9 proved occupancy raises achieved HBM BW
// (1.3->2.0 TB/s at 45%); R4's TQ=16 failure was L3-bound K/V (no affinity),
// fixed here by XCD-batch affinity (R5) keeping K_b+V_b^T (2 MB) L2-resident.
// Swapped QK^T (R7): acc[nt][r] = S^T[key=wave*256+nt*16+quad*4+r][q=i0+l16]
// -> int4 mask loads fused per-nt (R8), float4 attn writes batched per row
// (R3/R9 write-granularity law), raw lgkm barrier before PV (R8).
__global__ __launch_bounds__(512, 4) void attn_mfma(
    const float* __restrict__ qf, const short* __restrict__ kb,
    const short* __restrict__ vtb, const int* __restrict__ maskg,
    float* __restrict__ outg, float* __restrict__ attng)
{
    const int b = blockIdx.x & 7;              // XCD-affine batch
    const int i0 = (blockIdx.x >> 3) * TQ;     // q-tile within batch
    const int tid = threadIdx.x;
    const int wave = tid >> 6, lane = tid & 63;
    const int quad = lane >> 4, l16 = lane & 15;

    __shared__ short p_lds[TQ][PSTRIDE];       // 64.25 KB
    __shared__ float red[8][TQ];               // 512 B

    // ---------- Q fp32 -> bf16 in-register (row q = i0 + l16) ----------
    bf16x8 aq[8];
    const float* qbase = qf + ((size_t)b * S + i0 + l16) * D;
    #pragma unroll
    for (int ks = 0; ks < 8; ++ks) {
        const float* p = qbase + ks * 32 + quad * 8;
        float4 x0 = *(const float4*)p;
        float4 x1 = *(const float4*)(p + 4);
        bf16x8 a;
        a[0] = f2bf(x0.x); a[1] = f2bf(x0.y); a[2] = f2bf(x0.z); a[3] = f2bf(x0.w);
        a[4] = f2bf(x1.x); a[5] = f2bf(x1.y); a[6] = f2bf(x1.z); a[7] = f2bf(x1.w);
        aq[ks] = a;
    }

    f32x4 acc[16];
    #pragma unroll
    for (int nt = 0; nt < 16; ++nt)
        acc[nt] = f32x4{0.f, 0.f, 0.f, 0.f};

    // ---------- phase A: S^T = K Q^T with mask+exp+rsum fused per nt ----------
    float rsum = 0.f;
    const short* kbase = kb + (size_t)b * S * D;
    const int* mrow = maskg + ((size_t)b * S + i0 + l16) * S + wave * 256 + quad * 4;

    #pragma unroll
    for (int nt = 0; nt < 16; ++nt) {
        const int n0 = wave * 256 + nt * 16;
        int4 m = *(const int4*)(mrow + nt * 16);   // 16 B/lane mask load
        bf16x8 bk[8];
        #pragma unroll
        for (int ks = 0; ks < 8; ++ks)
            bk[ks] = *(const bf16x8*)(kbase + (size_t)(n0 + l16) * D + ks * 32 + quad * 8);
        #pragma unroll
        for (int ks = 0; ks < 8; ++ks)
            acc[nt] = __builtin_amdgcn_mfma_f32_16x16x32_bf16(bk[ks], aq[ks], acc[nt], 0, 0, 0);
        const int mm[4] = {m.x, m.y, m.z, m.w};
        #pragma unroll
        for (int r = 0; r < 4; ++r) {
            float e = mm[r] ? __expf(acc[nt][r] * SCALE) : 0.0f;  // exp(-1e9)->0 == ref
            acc[nt][r] = e;
            rsum += e;
        }
    }

    // ---------- reduce row-sum: 4 quads (shfl) then 8 waves (LDS) ----------
    {
        float v = rsum;
        v += __shfl_xor(v, 16); v += __shfl_xor(v, 32);
        if (quad == 0) red[wave][l16] = v;
    }
    __syncthreads();   // cheap: no outstanding global stores yet

    float inv;
    {
        float tot = 0.f;
        #pragma unroll
        for (int w = 0; w < 8; ++w) tot += red[w][l16];
        inv = 1.0f / tot;
    }

    // ---------- phase B: normalize, attn float4 writes (batched per row), P stash ----------
    {
        float* arow = attng + ((size_t)b * S + i0 + l16) * S + wave * 256 + quad * 4;
        #pragma unroll
        for (int nt = 0; nt < 16; ++nt) {
            float p0 = acc[nt][0] * inv;
            float p1 = acc[nt][1] * inv;
            float p2 = acc[nt][2] * inv;
            float p3 = acc[nt][3] * inv;
            float4 p4; p4.x = p0; p4.y = p1; p4.z = p2; p4.w = p3;
            short4 pb; pb.x = f2bf(p0); pb.y = f2bf(p1); pb.z = f2bf(p2); pb.w = f2bf(p3);
            *(float4*)(arow + nt * 16) = p4;
            *(short4*)&p_lds[l16][wave * 256 + nt * 16 + quad * 4] = pb;
        }
    }

    // raw barrier: wait LDS only; the 64 KB/block attn store stream retires
    // under phase C's loads/MFMAs instead of a vmcnt(0) drain (R8).
    asm volatile("s_waitcnt lgkmcnt(0)" ::: "memory");
    __builtin_amdgcn_s_barrier();
    asm volatile("" ::: "memory");

    // ---------- phase C: out = P V (wave w owns dims [w*32, w*32+32)) ----------
    f32x4 oacc[2];
    #pragma unroll
    for (int nc = 0; nc < 2; ++nc) oacc[nc] = f32x4{0.f, 0.f, 0.f, 0.f};

    const short* vbase = vtb + (size_t)b * D * S;
    const int nb = wave * 32;
    for (int ks = 0; ks < 64; ++ks) {
        bf16x8 ap = *(const bf16x8*)&p_lds[l16][ks * 32 + quad * 8];
        bf16x8 bv0 = *(const bf16x8*)(vbase + (size_t)(nb + l16) * S + ks * 32 + quad * 8);
        bf16x8 bv1 = *(const bf16x8*)(vbase + (size_t)(nb + 16 + l16) * S + ks * 32 + quad * 8);
        oacc[0] = __builtin_amdgcn_mfma_f32_16x16x32_bf16(ap, bv0, oacc[0], 0, 0, 0);
        oacc[1] = __builtin_amdgcn_mfma_f32_16x16x32_bf16(ap, bv1, oacc[1], 0, 0, 0);
    }

    #pragma unroll
    for (int nc = 0; nc < 2; ++nc)
        #pragma unroll
        for (int r = 0; r < 4; ++r) {
            int row = i0 + quad * 4 + r;
            int col = nb + nc * 16 + l16;
            outg[((size_t)b * S + row) * D + col] = oacc[nc][r];
        }
}

extern "C" void kernel_launch(void* const* d_in, const int* in_sizes, int n_in,
                              void* d_out, int out_size, void* d_ws, size_t ws_size,
                              hipStream_t stream) {
    const float* q    = (const float*)d_in[0];
    const float* k    = (const float*)d_in[1];
    const float* v    = (const float*)d_in[2];
    const int*   mask = (const int*)d_in[3];
    float* out  = (float*)d_out;
    float* attn = out + (size_t)B * S * D;     // tuple order: (out, attn)

    const size_t N = (size_t)B * S * D;        // 4,194,304 elements
    short* kb  = (short*)d_ws;                 // 8 MB
    short* vtb = kb + N;                       // 8 MB (transposed V)

    prepass<<<dim3(5120), 256, 0, stream>>>(k, v, kb, vtb);
    attn_mfma<<<dim3((S / TQ) * B), 512, 0, stream>>>(q, kb, vtb, mask, out, attn);
}

// Round 11
// 507.647 us; speedup vs baseline: 1.1346x; 1.0206x over previous
//
#include <hip/hip_runtime.h>

constexpr int B = 8, S = 2048, D = 256;
constexpr int TQ = 32;              // query rows per block
constexpr float SCALE = 0.0625f;    // 1/sqrt(256)
constexpr int PSTRIDE = 2056;       // 2048 + 8 bf16 pad

typedef __attribute__((ext_vector_type(8))) short bf16x8;  // 8 bf16 in 4 VGPRs
typedef __attribute__((ext_vector_type(4))) float f32x4;

__device__ __forceinline__ short f2bf(float f) {
    union { float f; unsigned u; } c; c.f = f;
    unsigned u = c.u + 0x7fffu + ((c.u >> 16) & 1u);   // RNE
    return (short)(u >> 16);
}

// ---- minimal pre-pass: convK | transposeV ----
__global__ __launch_bounds__(256) void prepass(
    const float* __restrict__ k, const float* __restrict__ v,
    short* __restrict__ kb, short* __restrict__ vtb)
{
    __shared__ float tile[64][65];
    const int blk = blockIdx.x;
    const int tid = threadIdx.x;

    if (blk < 4096) {
        int i = blk * 256 + tid;
        float4 x = ((const float4*)k)[i];
        short4 o; o.x = f2bf(x.x); o.y = f2bf(x.y); o.z = f2bf(x.z); o.w = f2bf(x.w);
        ((short4*)kb)[i] = o;
    } else {
        int blk2 = blk - 4096;
        int b = blk2 >> 7, rem = blk2 & 127;
        int d0 = (rem & 3) * 64, k0 = (rem >> 2) * 64;
        int tr = tid >> 4, tc = tid & 15;
        const float* vb = v + (size_t)b * S * D;
        #pragma unroll
        for (int r = 0; r < 4; ++r) {
            int key = r * 16 + tr;
            float4 x = *(const float4*)(vb + (size_t)(k0 + key) * D + d0 + tc * 4);
            tile[key][tc * 4 + 0] = x.x; tile[key][tc * 4 + 1] = x.y;
            tile[key][tc * 4 + 2] = x.z; tile[key][tc * 4 + 3] = x.w;
        }
        __syncthreads();
        short* vtbb = vtb + (size_t)b * D * S;
        #pragma unroll
        for (int r = 0; r < 4; ++r) {
            int d = r * 16 + tr;
            short4 o;
            o.x = f2bf(tile[tc * 4 + 0][d]); o.y = f2bf(tile[tc * 4 + 1][d]);
            o.z = f2bf(tile[tc * 4 + 2][d]); o.w = f2bf(tile[tc * 4 + 3][d]);
            *(short4*)(vtbb + (size_t)(d0 + d) * S + k0 + tc * 4) = o;
        }
    }
}

// ---- main fused kernel: 1024 threads (16 waves), 1 block = 32 q-rows x 1 batch ----
// SAME block work as R8, 2x the waves: wave = (wh = q-half, wk = key-range).
// Per wave: 16 q-rows x 256 keys -> acc 64 f32 + aq 32 regs, fits 128-VGPR
// bound for 16 waves/CU (4/SIMD, 2x R8's TLP). K/V still read ONCE per block
// (the R4/R10 TQ=16 failure was per-block K/V instruction doubling; this
// avoids it). Swapped QK^T (R7), int4 mask fused per-nt (R8), float4 attn
// writes batched per row (R3/R9 law), raw lgkm barrier (R8), XCD affinity (R5).
__global__ __launch_bounds__(1024, 4) void attn_mfma(
    const float* __restrict__ qf, const short* __restrict__ kb,
    const short* __restrict__ vtb, const int* __restrict__ maskg,
    float* __restrict__ outg, float* __restrict__ attng)
{
    const int b = blockIdx.x & 7;              // XCD-affine batch
    const int i0 = (blockIdx.x >> 3) * TQ;     // q-tile within batch
    const int tid = threadIdx.x;
    const int wave = tid >> 6, lane = tid & 63;
    const int quad = lane >> 4, l16 = lane & 15;
    const int wh = wave >> 3;                  // q-half: rows [wh*16, wh*16+16)
    const int wk = wave & 7;                   // key-range: [wk*256, wk*256+256)

    __shared__ short p_lds[TQ][PSTRIDE];       // 128.5 KB
    __shared__ float red[16][16];              // 1 KB

    // ---------- Q fp32 -> bf16 in-register (row q = i0 + wh*16 + l16) ----------
    bf16x8 aq[8];
    const float* qbase = qf + ((size_t)b * S + i0 + wh * 16 + l16) * D;
    #pragma unroll
    for (int ks = 0; ks < 8; ++ks) {
        const float* p = qbase + ks * 32 + quad * 8;
        float4 x0 = *(const float4*)p;
        float4 x1 = *(const float4*)(p + 4);
        bf16x8 a;
        a[0] = f2bf(x0.x); a[1] = f2bf(x0.y); a[2] = f2bf(x0.z); a[3] = f2bf(x0.w);
        a[4] = f2bf(x1.x); a[5] = f2bf(x1.y); a[6] = f2bf(x1.z); a[7] = f2bf(x1.w);
        aq[ks] = a;
    }

    f32x4 acc[16];
    #pragma unroll
    for (int nt = 0; nt < 16; ++nt)
        acc[nt] = f32x4{0.f, 0.f, 0.f, 0.f};

    // ---------- phase A: S^T = K Q^T with mask+exp+rsum fused per nt ----------
    float rsum = 0.f;
    const short* kbase = kb + (size_t)b * S * D;
    const int* mrow = maskg + ((size_t)b * S + i0 + wh * 16 + l16) * S + wk * 256 + quad * 4;

    #pragma unroll
    for (int nt = 0; nt < 16; ++nt) {
        const int n0 = wk * 256 + nt * 16;
        int4 m = *(const int4*)(mrow + nt * 16);   // 16 B/lane mask load
        bf16x8 bk[8];
        #pragma unroll
        for (int ks = 0; ks < 8; ++ks)
            bk[ks] = *(const bf16x8*)(kbase + (size_t)(n0 + l16) * D + ks * 32 + quad * 8);
        #pragma unroll
        for (int ks = 0; ks < 8; ++ks)
            acc[nt] = __builtin_amdgcn_mfma_f32_16x16x32_bf16(bk[ks], aq[ks], acc[nt], 0, 0, 0);
        float e;
        e = m.x ? __expf(acc[nt][0] * SCALE) : 0.0f; acc[nt][0] = e; rsum += e;
        e = m.y ? __expf(acc[nt][1] * SCALE) : 0.0f; acc[nt][1] = e; rsum += e;
        e = m.z ? __expf(acc[nt][2] * SCALE) : 0.0f; acc[nt][2] = e; rsum += e;
        e = m.w ? __expf(acc[nt][3] * SCALE) : 0.0f; acc[nt][3] = e; rsum += e;
    }

    // ---------- reduce row-sum: 4 quads (shfl) then 8 key-range waves (LDS) ----------
    {
        float v = rsum;
        v += __shfl_xor(v, 16); v += __shfl_xor(v, 32);
        if (quad == 0) red[wave][l16] = v;
    }
    __syncthreads();   // no outstanding global stores yet

    float inv;
    {
        float tot = 0.f;
        #pragma unroll
        for (int j = 0; j < 8; ++j) tot += red[wh * 8 + j][l16];
        inv = 1.0f / tot;
    }

    // ---------- phase B: normalize, attn float4 writes (batched per row), P stash ----------
    {
        float* arow = attng + ((size_t)b * S + i0 + wh * 16 + l16) * S + wk * 256 + quad * 4;
        #pragma unroll
        for (int nt = 0; nt < 16; ++nt) {
            float p0 = acc[nt][0] * inv;
            float p1 = acc[nt][1] * inv;
            float p2 = acc[nt][2] * inv;
            float p3 = acc[nt][3] * inv;
            float4 p4; p4.x = p0; p4.y = p1; p4.z = p2; p4.w = p3;
            short4 pb; pb.x = f2bf(p0); pb.y = f2bf(p1); pb.z = f2bf(p2); pb.w = f2bf(p3);
            *(float4*)(arow + nt * 16) = p4;
            *(short4*)&p_lds[wh * 16 + l16][wk * 256 + nt * 16 + quad * 4] = pb;
        }
    }

    // raw barrier: wait LDS only; the attn store stream retires under phase C
    // instead of a vmcnt(0) drain (R8).
    asm volatile("s_waitcnt lgkmcnt(0)" ::: "memory");
    __builtin_amdgcn_s_barrier();
    asm volatile("" ::: "memory");

    // ---------- phase C: out = P V (wave (wh,wk) owns q-half wh, dims [wk*32, wk*32+32)) ----------
    f32x4 oacc[2];
    #pragma unroll
    for (int nc = 0; nc < 2; ++nc) oacc[nc] = f32x4{0.f, 0.f, 0.f, 0.f};

    const short* vbase = vtb + (size_t)b * D * S;
    const int nb = wk * 32;
    for (int ks = 0; ks < 64; ++ks) {
        bf16x8 ap = *(const bf16x8*)&p_lds[wh * 16 + l16][ks * 32 + quad * 8];
        bf16x8 bv0 = *(const bf16x8*)(vbase + (size_t)(nb + l16) * S + ks * 32 + quad * 8);
        bf16x8 bv1 = *(const bf16x8*)(vbase + (size_t)(nb + 16 + l16) * S + ks * 32 + quad * 8);
        oacc[0] = __builtin_amdgcn_mfma_f32_16x16x32_bf16(ap, bv0, oacc[0], 0, 0, 0);
        oacc[1] = __builtin_amdgcn_mfma_f32_16x16x32_bf16(ap, bv1, oacc[1], 0, 0, 0);
    }

    #pragma unroll
    for (int nc = 0; nc < 2; ++nc)
        #pragma unroll
        for (int r = 0; r < 4; ++r) {
            int row = i0 + wh * 16 + quad * 4 + r;
            int col = nb + nc * 16 + l16;
            outg[((size_t)b * S + row) * D + col] = oacc[nc][r];
        }
}

extern "C" void kernel_launch(void* const* d_in, const int* in_sizes, int n_in,
                              void* d_out, int out_size, void* d_ws, size_t ws_size,
                              hipStream_t stream) {
    const float* q    = (const float*)d_in[0];
    const float* k    = (const float*)d_in[1];
    const float* v    = (const float*)d_in[2];
    const int*   mask = (const int*)d_in[3];
    float* out  = (float*)d_out;
    float* attn = out + (size_t)B * S * D;     // tuple order: (out, attn)

    const size_t N = (size_t)B * S * D;        // 4,194,304 elements
    short* kb  = (short*)d_ws;                 // 8 MB
    short* vtb = kb + N;                       // 8 MB (transposed V)

    prepass<<<dim3(5120), 256, 0, stream>>>(k, v, kb, vtb);
    attn_mfma<<<dim3((S / TQ) * B), 1024, 0, stream>>>(q, kb, vtb, mask, out, attn);
}